// Round 17
// baseline (4671.579 us; speedup 1.0000x reference)
//
#include <hip/hip_runtime.h>
#include <hip/hip_bf16.h>

#define B    256
#define S    192
#define F    64
#define HD   1024
#define PRED 48
#define TSTART (S - 1 - PRED)   // 143
#define NSLOT 48

typedef __attribute__((ext_vector_type(8))) short short8;
typedef __attribute__((ext_vector_type(4))) float f32x4;
typedef unsigned int u32;

static __device__ __forceinline__ short f2bf(float f) {
    __hip_bfloat16 h = __float2bfloat16(f);
    return *reinterpret_cast<short*>(&h);
}
static __device__ __forceinline__ f32x4 mfma16(short8 a, short8 b, f32x4 c) {
    return __builtin_amdgcn_mfma_f32_16x16x32_bf16(a, b, c, 0, 0, 0);
}
static __device__ __forceinline__ short8 ld8(const short* p) {
    return *reinterpret_cast<const short8*>(p);
}
// sc1 write-through store (MALL = device coherence point). R4-R16-proven.
// Readers: PLAIN cached loads on 48-slot-rotated fresh addresses.
static __device__ __forceinline__ void st_state(short* p, short v) {
    __hip_atomic_store(p, v, __ATOMIC_RELAXED, __HIP_MEMORY_SCOPE_AGENT);
}
static __device__ __forceinline__ u32 ld_flag(const u32* p) {
    return __hip_atomic_load(p, __ATOMIC_RELAXED, __HIP_MEMORY_SCOPE_AGENT);
}
static __device__ __forceinline__ void st_flag(u32* p, u32 v) {
    __hip_atomic_store(p, v, __ATOMIC_RELAXED, __HIP_MEMORY_SCOPE_AGENT);
}

// Preload all 16 peer flags as INDEPENDENT loads (single latency exposure),
// spin only on stragglers. Replaces the serial 16x poll chain.
static __device__ __forceinline__ void checkflags(const u32* fb, int rt, u32 tgt) {
    u32 fv[16];
#pragma unroll
    for (int i = 0; i < 16; ++i) fv[i] = ld_flag(fb + (rt * 16 + i) * 32);
#pragma unroll
    for (int i = 0; i < 16; ++i)
        if (fv[i] < tgt)
            while (ld_flag(fb + (rt * 16 + i) * 32) < tgt)
                __builtin_amdgcn_s_sleep(1);
}

// ---------------------------------------------------------------------------
// prep kernels (proven)
// ---------------------------------------------------------------------------
__global__ void fold_kernel(const float* __restrict__ Wh,
                            const float* __restrict__ Wih0,
                            float* __restrict__ Wfold) {
    const int n = (blockIdx.x & 3) * 256 + threadIdx.x;
    const int f = blockIdx.x >> 2;
    float a = 0.f;
#pragma unroll 16
    for (int k = 0; k < HD; ++k)
        a += Wh[f * HD + k] * Wih0[(size_t)k * HD + n];
    Wfold[f * HD + n] = a;
}

__global__ void bias_kernel(const float* __restrict__ bh,
                            const float* __restrict__ Wih0,
                            const float* __restrict__ bih,
                            const float* __restrict__ bhh,
                            float* __restrict__ bf0,
                            float* __restrict__ bf1) {
    __shared__ float red[256];
    const int nl = threadIdx.x & 15;
    const int kc = threadIdx.x >> 4;
    const int n  = blockIdx.x * 16 + nl;
    float a = 0.f;
#pragma unroll 8
    for (int k = kc * 64; k < kc * 64 + 64; ++k)
        a += bh[k] * Wih0[(size_t)k * HD + n];
    red[threadIdx.x] = a;
    __syncthreads();
    if (kc == 0) {
        float s = 0.f;
#pragma unroll
        for (int j = 0; j < 16; ++j) s += red[j * 16 + nl];
        bf0[n] = s + bih[n] + bhh[n];
        bf1[n] = bih[HD + n] + bhh[HD + n];
    }
}

__global__ void transpose_cast(const float* __restrict__ src,
                               short* __restrict__ dst, int K, int N) {
    __shared__ float tile[64][65];
    const int nk = K >> 6;
    const int bk = blockIdx.x % nk;
    const int bn = blockIdx.x / nk;
    const int i  = threadIdx.x;
    {
        const int c4 = (i & 15) * 4;
        for (int it = 0; it < 4; ++it) {
            const int k = (i >> 4) + it * 16;
            const float4 v = *reinterpret_cast<const float4*>(
                &src[(size_t)(bk * 64 + k) * N + bn * 64 + c4]);
            tile[k][c4 + 0] = v.x; tile[k][c4 + 1] = v.y;
            tile[k][c4 + 2] = v.z; tile[k][c4 + 3] = v.w;
        }
    }
    __syncthreads();
    {
        const int n  = i >> 2;
        const int kb = (i & 3) * 16;
        short* dp = &dst[(size_t)(bn * 64 + n) * K + bk * 64 + kb];
#pragma unroll
        for (int j = 0; j < 16; ++j) dp[j] = f2bf(tile[kb + j][n]);
    }
}

__global__ void xcast(const float* __restrict__ x, short* __restrict__ xb) {
    const size_t i = ((size_t)blockIdx.x * 256 + threadIdx.x) * 4;
    const float4 v = *reinterpret_cast<const float4*>(&x[i]);
    short4 o;
    o.x = f2bf(v.x); o.y = f2bf(v.y); o.z = f2bf(v.z); o.w = f2bf(v.w);
    *reinterpret_cast<short4*>(&xb[i]) = o;
}

// ---------------------------------------------------------------------------
// gemm_du: K=1024, 16x16 frag. A direct from global state: ALL 32 A-loads
// issued up front as independent loads (128 VGPR; consumed once, so no
// rematerialization is possible — unlike R16's loop-invariant wr[]);
// sched_barrier(0) pins the issue order. B streamed 4-deep from L2-hot
// weights. One latency exposure for A, then MFMA/B-stream bound.
// ---------------------------------------------------------------------------
static __device__ __forceinline__ f32x4 gemm_du(const short* __restrict__ ap,
                                                const short* __restrict__ bp,
                                                f32x4 acc_in) {
    short8 av[32];
#pragma unroll
    for (int c = 0; c < 32; ++c) av[c] = ld8(ap + c * 32);
    __builtin_amdgcn_sched_barrier(0);           // keep A issues up front
    f32x4 acc0 = acc_in, acc1 = {0.f, 0.f, 0.f, 0.f};
    short8 b0[4], b1[4];
#pragma unroll
    for (int j = 0; j < 4; ++j) b0[j] = ld8(bp + j * 32);
#pragma unroll
    for (int g = 0; g < 8; ++g) {
        if (g < 7) {
            short8* nb = (g & 1) ? b0 : b1;
#pragma unroll
            for (int j = 0; j < 4; ++j) nb[j] = ld8(bp + (g + 1) * 128 + j * 32);
        }
        const short8* cb = (g & 1) ? b1 : b0;
#pragma unroll
        for (int j = 0; j < 4; ++j) {
            if (j & 1) acc1 = mfma16(av[g * 4 + j], cb[j], acc1);
            else       acc0 = mfma16(av[g * 4 + j], cb[j], acc0);
        }
    }
    return acc0 + acc1;
}

// ---------------------------------------------------------------------------
// Persistent skewed recurrence (R15 map + R11-proven flag protocol).
// R17: NO LDS, NO staging — direct-global A (R2-proven fragment addressing),
// flag PRELOAD (independent loads, not serial polls), ONE barrier per phase
// (store-drain before flag set). Everything else frozen.
// bid -> (layer, rt, ct): xcd=bid&7, u=bid>>3; layer=u&1;
// rt=((xcd&3)<<1)|((u>>1)&1); ct=((xcd>>2)<<3)|((u>>2)&7).  [perf heuristic,
// correctness placement-free]
// ---------------------------------------------------------------------------
__global__ __launch_bounds__(512) void rnn_pers(
    const short* __restrict__ xbf,
    const short* __restrict__ WfoldT, const float* __restrict__ bf0,
    const short* __restrict__ WhhT0, const short* __restrict__ WihT1,
    const short* __restrict__ WhhT1, const float* __restrict__ bf1,
    short* h0h, short* h1h, u32* flags0, u32* flags1) {

    const int bid   = blockIdx.x;
    const int xcd   = bid & 7;
    const int u     = bid >> 3;
    const int layer = u & 1;
    const int rt    = ((xcd & 3) << 1) | ((u >> 1) & 1);   // 0..7
    const int ct    = ((xcd >> 2) << 3) | ((u >> 2) & 7);  // 0..15
    const int w     = threadIdx.x >> 6;
    const int mh    = w & 1;
    const int nq    = w >> 1;
    const int l     = threadIdx.x & 63;
    const int lr    = l & 15, kg = l >> 4;
    const int row0  = rt * 32;
    const int m0    = row0 + mh * 16;
    const int n0    = ct * 64 + nq * 16;
    const int col   = n0 + lr;
    const int rb    = m0 + kg * 4;
    const int tid   = threadIdx.x;

    const float bb = (layer ? bf1 : bf0)[col];
    u32* myflag = (layer ? flags1 : flags0) + (rt * 16 + ct) * 32;
    const size_t arow_off = (size_t)(m0 + lr) * HD + kg * 8;

    if (layer == 0) {
        const short* wf = WfoldT + (size_t)col * F + kg * 8;
        const short8 wf0 = ld8(wf), wf1 = ld8(wf + 32);
        const short* whh0p = WhhT0 + (size_t)col * HD + kg * 8;
        for (int k = 0; k < S - 1; ++k) {
            const short* xp = xbf + ((size_t)(m0 + lr) * S + k) * F + kg * 8;
            f32x4 acc = {0.f, 0.f, 0.f, 0.f};
            acc = mfma16(ld8(xp),      wf0, acc);
            acc = mfma16(ld8(xp + 32), wf1, acc);
            if (k > 0) {
                checkflags(flags0, rt, (u32)k);
                acc = gemm_du(h0h + (size_t)((k - 1) % NSLOT) * B * HD + arow_off,
                              whh0p, acc);
            }
            // WAR: slot k%48 overwrite needs L1 past phase k-45 (R16-proven bound)
            if (k >= 46) checkflags(flags1, rt, (u32)(k - 45));
            short* hd = h0h + (size_t)(k % NSLOT) * B * HD;
#pragma unroll
            for (int r = 0; r < 4; ++r)
                st_state(&hd[(size_t)(rb + r) * HD + col],
                         f2bf(tanhf(acc[r] + bb)));
            __syncthreads();                      // drain sc1 stores (vmcnt 0)
            if (tid == 0) st_flag(myflag, (u32)(k + 1));
        }
    } else {
        if (tid == 0) st_flag(myflag, 1u);        // phase 0: no-op
        const short* wih1p = WihT1 + (size_t)col * HD + kg * 8;
        const short* whh1p = WhhT1 + (size_t)col * HD + kg * 8;
        for (int k = 1; k < S; ++k) {
            const int t = k - 1;
            // h0 path: L0 runs ~45 ahead -> flags0 check is ~instant
            checkflags(flags0, rt, (u32)k);
            f32x4 acc = {0.f, 0.f, 0.f, 0.f};
            acc = gemm_du(h0h + (size_t)((k - 1) % NSLOT) * B * HD + arow_off,
                          wih1p, acc);
            // h1 path: the true recurrent chain
            if (t > 0) {
                checkflags(flags1, rt, (u32)k);
                acc = gemm_du(h1h + (size_t)((t - 1) % NSLOT) * B * HD + arow_off,
                              whh1p, acc);
            }
            short* hd = h1h + (size_t)(t % NSLOT) * B * HD;
#pragma unroll
            for (int r = 0; r < 4; ++r)
                st_state(&hd[(size_t)(rb + r) * HD + col],
                         f2bf(tanhf(acc[r] + bb)));
            __syncthreads();                      // drain sc1 stores
            if (tid == 0) st_flag(myflag, (u32)(k + 1));
        }
    }
}

// ---------------------------------------------------------------------------
// outgemm: out[b][p][f] = relu(h1(143+p)[b]) @ WoT + bo (history slots,
// bijective (143+p)%48; slots t>=143 never overwritten). Kernel boundary
// gives coherence.
// ---------------------------------------------------------------------------
__global__ __launch_bounds__(256) void outgemm(
    const short* __restrict__ h1h, const short* __restrict__ WoT,
    const float* __restrict__ bo, float* __restrict__ out) {
    const int w = threadIdx.x >> 6, l = threadIdx.x & 63;
    const int lr = l & 15, kg = l >> 4;
    const int m0 = blockIdx.x * 64 + w * 16;
    const int arow = m0 + lr;                 // b*48+p
    const u32 bidx = (u32)arow / 48u;
    const u32 p    = (u32)arow % 48u;
    const u32 slot = (143u + p) % 48u;

    f32x4 acc[4] = {{0.f,0.f,0.f,0.f},{0.f,0.f,0.f,0.f},
                    {0.f,0.f,0.f,0.f},{0.f,0.f,0.f,0.f}};
    const short* ap = h1h + ((size_t)slot * B + bidx) * HD + kg * 8;
    const short* bp = WoT + (size_t)lr * HD + kg * 8;
#pragma unroll 4
    for (int k0 = 0; k0 < HD; k0 += 32) {
        short8 a = ld8(ap + k0);
#pragma unroll
        for (int j = 0; j < 8; ++j) a[j] = (a[j] < 0) ? (short)0 : a[j];  // relu
#pragma unroll
        for (int c = 0; c < 4; ++c)
            acc[c] = mfma16(a, ld8(bp + (size_t)c * 16 * HD + k0), acc[c]);
    }
    const int rb = m0 + kg * 4;
#pragma unroll
    for (int c = 0; c < 4; ++c) {
        const float bbv = bo[c * 16 + lr];
#pragma unroll
        for (int r = 0; r < 4; ++r)
            out[(size_t)(rb + r) * F + c * 16 + lr] = acc[c][r] + bbv;
    }
}

// ---------------------------------------------------------------------------
extern "C" void kernel_launch(void* const* d_in, const int* in_sizes, int n_in,
                              void* d_out, int out_size, void* d_ws, size_t ws_size,
                              hipStream_t stream) {
    const float* x   = (const float*)d_in[0];
    const float* Wh  = (const float*)d_in[1];
    const float* bh  = (const float*)d_in[2];
    const float* Wih = (const float*)d_in[3];
    const float* Whh = (const float*)d_in[4];
    const float* bih = (const float*)d_in[5];
    const float* bhh = (const float*)d_in[6];
    const float* Wo  = (const float*)d_in[7];
    const float* bo  = (const float*)d_in[8];
    float* out = (float*)d_out;

    char* p = (char*)d_ws;
    float* Wfold  = (float*)p; p += (size_t)F * HD * 4;
    float* bf0    = (float*)p; p += HD * 4;
    float* bf1    = (float*)p; p += HD * 4;
    short* WfoldT = (short*)p; p += (size_t)HD * F * 2;
    short* WhhT0  = (short*)p; p += (size_t)HD * HD * 2;
    short* WihT1  = (short*)p; p += (size_t)HD * HD * 2;
    short* WhhT1  = (short*)p; p += (size_t)HD * HD * 2;
    short* WoT    = (short*)p; p += (size_t)F * HD * 2;
    short* h0h    = (short*)p; p += (size_t)NSLOT * B * HD * 2;   // 24 MB
    short* h1h    = (short*)p; p += (size_t)NSLOT * B * HD * 2;   // 24 MB
    short* xbf    = (short*)p; p += (size_t)B * S * F * 2;
    u32*   sync   = (u32*)p;  p += 65536;
    // sync: flags0 = 128 flags x 128B (16KB) | flags1 at +16KB

    hipMemsetAsync(sync, 0, 65536, stream);

    fold_kernel<<<256, 256, 0, stream>>>(Wh, Wih, Wfold);
    bias_kernel<<<64, 256, 0, stream>>>(bh, Wih, bih, bhh, bf0, bf1);
    transpose_cast<<<16, 256, 0, stream>>>(Wfold, WfoldT, F, HD);
    transpose_cast<<<256, 256, 0, stream>>>(Whh, WhhT0, HD, HD);
    transpose_cast<<<256, 256, 0, stream>>>(Wih + (size_t)HD * HD, WihT1, HD, HD);
    transpose_cast<<<256, 256, 0, stream>>>(Whh + (size_t)HD * HD, WhhT1, HD, HD);
    transpose_cast<<<16, 256, 0, stream>>>(Wo, WoT, HD, F);
    xcast<<<(B * S * F) / (256 * 4), 256, 0, stream>>>(x, xbf);

    u32* flags0 = sync;
    u32* flags1 = sync + 4096;
    void* args[] = {
        (void*)&xbf, (void*)&WfoldT, (void*)&bf0, (void*)&WhhT0,
        (void*)&WihT1, (void*)&WhhT1, (void*)&bf1,
        (void*)&h0h, (void*)&h1h, (void*)&flags0, (void*)&flags1
    };
    hipLaunchCooperativeKernel((void*)rnn_pers, dim3(256), dim3(512),
                               args, 0, stream);

    outgemm<<<192, 256, 0, stream>>>(h1h, WoT, bo, out);
}

// Round 18
// 2174.620 us; speedup vs baseline: 2.1482x; 2.1482x over previous
//
#include <hip/hip_runtime.h>
#include <hip/hip_bf16.h>

#define B    256
#define S    192
#define F    64
#define HD   1024
#define PRED 48
#define TSTART (S - 1 - PRED)   // 143
#define NSLOT 48

typedef __attribute__((ext_vector_type(8))) short short8;
typedef __attribute__((ext_vector_type(4))) float f32x4;
typedef unsigned int u32;

static __device__ __forceinline__ short f2bf(float f) {
    __hip_bfloat16 h = __float2bfloat16(f);
    return *reinterpret_cast<short*>(&h);
}
static __device__ __forceinline__ f32x4 mfma16(short8 a, short8 b, f32x4 c) {
    return __builtin_amdgcn_mfma_f32_16x16x32_bf16(a, b, c, 0, 0, 0);
}
static __device__ __forceinline__ short8 ld8(const short* p) {
    return *reinterpret_cast<const short8*>(p);
}
// sc1 write-through store (MALL = device coherence point). R4-R17-proven.
// Readers: PLAIN cached loads on 48-slot-rotated fresh addresses.
static __device__ __forceinline__ void st_state(short* p, short v) {
    __hip_atomic_store(p, v, __ATOMIC_RELAXED, __HIP_MEMORY_SCOPE_AGENT);
}
static __device__ __forceinline__ u32 ld_flag(const u32* p) {
    return __hip_atomic_load(p, __ATOMIC_RELAXED, __HIP_MEMORY_SCOPE_AGENT);
}
static __device__ __forceinline__ void st_flag(u32* p, u32 v) {
    __hip_atomic_store(p, v, __ATOMIC_RELAXED, __HIP_MEMORY_SCOPE_AGENT);
}

// ---------------------------------------------------------------------------
// prep kernels (proven)
// ---------------------------------------------------------------------------
__global__ void fold_kernel(const float* __restrict__ Wh,
                            const float* __restrict__ Wih0,
                            float* __restrict__ Wfold) {
    const int n = (blockIdx.x & 3) * 256 + threadIdx.x;
    const int f = blockIdx.x >> 2;
    float a = 0.f;
#pragma unroll 16
    for (int k = 0; k < HD; ++k)
        a += Wh[f * HD + k] * Wih0[(size_t)k * HD + n];
    Wfold[f * HD + n] = a;
}

__global__ void bias_kernel(const float* __restrict__ bh,
                            const float* __restrict__ Wih0,
                            const float* __restrict__ bih,
                            const float* __restrict__ bhh,
                            float* __restrict__ bf0,
                            float* __restrict__ bf1) {
    __shared__ float red[256];
    const int nl = threadIdx.x & 15;
    const int kc = threadIdx.x >> 4;
    const int n  = blockIdx.x * 16 + nl;
    float a = 0.f;
#pragma unroll 8
    for (int k = kc * 64; k < kc * 64 + 64; ++k)
        a += bh[k] * Wih0[(size_t)k * HD + n];
    red[threadIdx.x] = a;
    __syncthreads();
    if (kc == 0) {
        float s = 0.f;
#pragma unroll
        for (int j = 0; j < 16; ++j) s += red[j * 16 + nl];
        bf0[n] = s + bih[n] + bhh[n];
        bf1[n] = bih[HD + n] + bhh[HD + n];
    }
}

__global__ void transpose_cast(const float* __restrict__ src,
                               short* __restrict__ dst, int K, int N) {
    __shared__ float tile[64][65];
    const int nk = K >> 6;
    const int bk = blockIdx.x % nk;
    const int bn = blockIdx.x / nk;
    const int i  = threadIdx.x;
    {
        const int c4 = (i & 15) * 4;
        for (int it = 0; it < 4; ++it) {
            const int k = (i >> 4) + it * 16;
            const float4 v = *reinterpret_cast<const float4*>(
                &src[(size_t)(bk * 64 + k) * N + bn * 64 + c4]);
            tile[k][c4 + 0] = v.x; tile[k][c4 + 1] = v.y;
            tile[k][c4 + 2] = v.z; tile[k][c4 + 3] = v.w;
        }
    }
    __syncthreads();
    {
        const int n  = i >> 2;
        const int kb = (i & 3) * 16;
        short* dp = &dst[(size_t)(bn * 64 + n) * K + bk * 64 + kb];
#pragma unroll
        for (int j = 0; j < 16; ++j) dp[j] = f2bf(tile[kb + j][n]);
    }
}

__global__ void xcast(const float* __restrict__ x, short* __restrict__ xb) {
    const size_t i = ((size_t)blockIdx.x * 256 + threadIdx.x) * 4;
    const float4 v = *reinterpret_cast<const float4*>(&x[i]);
    short4 o;
    o.x = f2bf(v.x); o.y = f2bf(v.y); o.z = f2bf(v.z); o.w = f2bf(v.w);
    *reinterpret_cast<short4*>(&xb[i]) = o;
}

// ---------------------------------------------------------------------------
// LDS layout (k-chunk-major, R11): addr = kc*2048 + r*64 + kg*16, 64KB/buffer.
// ---------------------------------------------------------------------------
static __device__ __forceinline__ void stage1(char* lds, const short* __restrict__ src,
                                              int row0) {
    const int tid = threadIdx.x;
#pragma unroll
    for (int it = 0; it < 8; ++it) {
        const int idx = it * 512 + tid;
        const int r   = (idx >> 2) & 31;
        const int off = ((idx >> 7) << 6) + ((idx & 3) << 4);
        const f32x4 v = *reinterpret_cast<const f32x4*>(
            (const char*)src + (size_t)(row0 + r) * 2048 + off);
        *reinterpret_cast<f32x4*>(lds + (idx << 4)) = v;
    }
}

// T14 split-staging: issue 8 global loads to regs early...
static __device__ __forceinline__ void pre_load(f32x4 (&pre)[8],
                                                const short* __restrict__ src,
                                                int row0) {
    const int tid = threadIdx.x;
#pragma unroll
    for (int it = 0; it < 8; ++it) {
        const int idx = it * 512 + tid;
        const int r   = (idx >> 2) & 31;
        const int off = ((idx >> 7) << 6) + ((idx & 3) << 4);
        pre[it] = *reinterpret_cast<const f32x4*>(
            (const char*)src + (size_t)(row0 + r) * 2048 + off);
    }
}
// ...write them to LDS late.
static __device__ __forceinline__ void pre_write(char* lds, const f32x4 (&pre)[8]) {
    const int tid = threadIdx.x;
#pragma unroll
    for (int it = 0; it < 8; ++it) {
        const int idx = it * 512 + tid;
        *reinterpret_cast<f32x4*>(lds + (idx << 4)) = pre[it];
    }
}

// gemmLG: 16x16 frag, K=1024; A from LDS, B streamed 8-deep (R13-proven).
static __device__ __forceinline__ f32x4 gemmLG(const char* ldsA,
                                               const short* __restrict__ bp,
                                               f32x4 acc_in) {
    f32x4 acc0 = acc_in, acc1 = {0.f,0.f,0.f,0.f};
    short8 b0[8], b1[8];
#pragma unroll
    for (int j = 0; j < 8; ++j) b0[j] = ld8(bp + j * 32);
#pragma unroll
    for (int c = 0; c < 4; ++c) {
        if (c < 3) {
            short8* nxt = (c & 1) ? b0 : b1;
#pragma unroll
            for (int j = 0; j < 8; ++j) nxt[j] = ld8(bp + (c + 1) * 256 + j * 32);
        }
        const short8* cur = (c & 1) ? b1 : b0;
#pragma unroll
        for (int j = 0; j < 8; ++j) {
            const short8 a = *reinterpret_cast<const short8*>(
                ldsA + (c * 8 + j) * 2048);
            if (j & 1) acc1 = mfma16(a, cur[j], acc1);
            else       acc0 = mfma16(a, cur[j], acc0);
        }
    }
    return acc0 + acc1;
}

// ---------------------------------------------------------------------------
// Persistent skewed recurrence (R15 map + flag protocol). R18: L1 pipelined —
// ldsA holds h0(k-1) at entry (written from prefetch regs at end of previous
// phase): gemm1 starts with zero wait; flags0(k+1) & flags1(k) polled
// concurrently (one barrier); next h0 prefetch flies under stage-h1+gemm2.
// ---------------------------------------------------------------------------
__global__ __launch_bounds__(512, 1) void rnn_pers(
    const short* __restrict__ xbf,
    const short* __restrict__ WfoldT, const float* __restrict__ bf0,
    const short* __restrict__ WhhT0, const short* __restrict__ WihT1,
    const short* __restrict__ WhhT1, const float* __restrict__ bf1,
    short* h0h, short* h1h, u32* flags0, u32* flags1) {

    extern __shared__ char lds[];                // 128 KB

    const int bid   = blockIdx.x;
    const int xcd   = bid & 7;
    const int u     = bid >> 3;
    const int layer = u & 1;
    const int rt    = ((xcd & 3) << 1) | ((u >> 1) & 1);   // 0..7
    const int ct    = ((xcd >> 2) << 3) | ((u >> 2) & 7);  // 0..15
    const int w     = threadIdx.x >> 6;
    const int mh    = w & 1;
    const int nq    = w >> 1;
    const int l     = threadIdx.x & 63;
    const int lr    = l & 15, kg = l >> 4;
    const int row0  = rt * 32;
    const int m0    = row0 + mh * 16;
    const int n0    = ct * 64 + nq * 16;
    const int col   = n0 + lr;
    const int rb    = m0 + kg * 4;
    const char* ldsA = lds + mh * 1024 + lr * 64 + kg * 16;

    const float bb = (layer ? bf1 : bf0)[col];
    u32* myflag = (layer ? flags1 : flags0) + (rt * 16 + ct) * 32;
    const int tid = threadIdx.x;

    if (layer == 0) {
        const short* wf = WfoldT + (size_t)col * F + kg * 8;
        const short8 wf0 = ld8(wf), wf1 = ld8(wf + 32);
        const short* whh0p = WhhT0 + (size_t)col * HD + kg * 8;
        for (int k = 0; k < S - 1; ++k) {
            const short* xp = xbf + ((size_t)(m0 + lr) * S + k) * F + kg * 8;
            const short8 xa0 = ld8(xp);
            const short8 xa1 = ld8(xp + 32);
            if (k > 0) {
                __syncthreads();
                if (tid < 16) {
                    const u32* f = flags0 + (rt * 16 + tid) * 32;
                    while (ld_flag(f) < (u32)k) __builtin_amdgcn_s_sleep(1);
                } else if (tid < 32 && k >= 46) {
                    const u32* f = flags1 + (rt * 16 + (tid - 16)) * 32;
                    while (ld_flag(f) < (u32)(k - 45)) __builtin_amdgcn_s_sleep(1);
                }
                __syncthreads();
                stage1(lds, h0h + (size_t)((k - 1) % NSLOT) * B * HD, row0);
                __syncthreads();
            }
            f32x4 acc = {0.f, 0.f, 0.f, 0.f};
            acc = mfma16(xa0, wf0, acc);
            acc = mfma16(xa1, wf1, acc);
            if (k > 0) acc = gemmLG(ldsA, whh0p, acc);
            short* hd = h0h + (size_t)(k % NSLOT) * B * HD;
#pragma unroll
            for (int r = 0; r < 4; ++r)
                st_state(&hd[(size_t)(rb + r) * HD + col],
                         f2bf(tanhf(acc[r] + bb)));
            __syncthreads();                      // drain sc1 stores (vmcnt 0)
            if (tid == 0) st_flag(myflag, (u32)(k + 1));
        }
    } else {
        if (tid == 0) st_flag(myflag, 1u);        // phase 0: no-op
        char* ldsBbuf = lds + 65536;
        const char* ldsB = ldsBbuf + mh * 1024 + lr * 64 + kg * 16;
        const short* wih1p = WihT1 + (size_t)col * HD + kg * 8;
        const short* whh1p = WhhT1 + (size_t)col * HD + kg * 8;

        // prologue: ldsA = h0(0)
        if (tid < 16) {
            const u32* f = flags0 + (rt * 16 + tid) * 32;
            while (ld_flag(f) < 1u) __builtin_amdgcn_s_sleep(1);
        }
        __syncthreads();
        stage1(lds, h0h, row0);
        __syncthreads();

        for (int k = 1; k < S; ++k) {
            const int t = k - 1;
            f32x4 acc = {0.f, 0.f, 0.f, 0.f};
            acc = gemmLG(ldsA, wih1p, acc);       // h0(k-1) pre-staged
            // concurrent polls: flags0(k+1) [instant] + flags1(k) [recurrent]
            if (tid < 16) {
                if (k + 1 < S) {
                    const u32* f = flags0 + (rt * 16 + tid) * 32;
                    while (ld_flag(f) < (u32)(k + 1)) __builtin_amdgcn_s_sleep(1);
                }
            } else if (tid < 32 && t > 0) {
                const u32* f = flags1 + (rt * 16 + (tid - 16)) * 32;
                while (ld_flag(f) < (u32)k) __builtin_amdgcn_s_sleep(1);
            }
            __syncthreads();
            f32x4 pre[8];
            if (k + 1 < S)
                pre_load(pre, h0h + (size_t)(k % NSLOT) * B * HD, row0);
            if (t > 0) {
                stage1(ldsBbuf, h1h + (size_t)((t - 1) % NSLOT) * B * HD, row0);
                __syncthreads();
                acc = gemmLG(ldsB, whh1p, acc);
            }
#pragma unroll
            for (int r = 0; r < 4; ++r)
                st_state(&h1h[(size_t)(t % NSLOT) * B * HD
                              + (size_t)(rb + r) * HD + col],
                         f2bf(tanhf(acc[r] + bb)));
            __syncthreads();                      // drains stores; gemm1 reads done
            if (tid == 0) st_flag(myflag, (u32)(k + 1));
            if (k + 1 < S) {
                pre_write(lds, pre);              // ldsA = h0(k) for next phase
                __syncthreads();
            }
        }
    }
}

// ---------------------------------------------------------------------------
// outgemm: out[b][p][f] = relu(h1(143+p)[b]) @ WoT + bo (history slots,
// bijective (143+p)%48). Kernel boundary gives coherence.
// ---------------------------------------------------------------------------
__global__ __launch_bounds__(256) void outgemm(
    const short* __restrict__ h1h, const short* __restrict__ WoT,
    const float* __restrict__ bo, float* __restrict__ out) {
    const int w = threadIdx.x >> 6, l = threadIdx.x & 63;
    const int lr = l & 15, kg = l >> 4;
    const int m0 = blockIdx.x * 64 + w * 16;
    const int arow = m0 + lr;                 // b*48+p
    const u32 bidx = (u32)arow / 48u;
    const u32 p    = (u32)arow % 48u;
    const u32 slot = (143u + p) % 48u;

    f32x4 acc[4] = {{0.f,0.f,0.f,0.f},{0.f,0.f,0.f,0.f},
                    {0.f,0.f,0.f,0.f},{0.f,0.f,0.f,0.f}};
    const short* ap = h1h + ((size_t)slot * B + bidx) * HD + kg * 8;
    const short* bp = WoT + (size_t)lr * HD + kg * 8;
#pragma unroll 4
    for (int k0 = 0; k0 < HD; k0 += 32) {
        short8 a = ld8(ap + k0);
#pragma unroll
        for (int j = 0; j < 8; ++j) a[j] = (a[j] < 0) ? (short)0 : a[j];  // relu
#pragma unroll
        for (int c = 0; c < 4; ++c)
            acc[c] = mfma16(a, ld8(bp + (size_t)c * 16 * HD + k0), acc[c]);
    }
    const int rb = m0 + kg * 4;
#pragma unroll
    for (int c = 0; c < 4; ++c) {
        const float bbv = bo[c * 16 + lr];
#pragma unroll
        for (int r = 0; r < 4; ++r)
            out[(size_t)(rb + r) * F + c * 16 + lr] = acc[c][r] + bbv;
    }
}

// ---------------------------------------------------------------------------
extern "C" void kernel_launch(void* const* d_in, const int* in_sizes, int n_in,
                              void* d_out, int out_size, void* d_ws, size_t ws_size,
                              hipStream_t stream) {
    const float* x   = (const float*)d_in[0];
    const float* Wh  = (const float*)d_in[1];
    const float* bh  = (const float*)d_in[2];
    const float* Wih = (const float*)d_in[3];
    const float* Whh = (const float*)d_in[4];
    const float* bih = (const float*)d_in[5];
    const float* bhh = (const float*)d_in[6];
    const float* Wo  = (const float*)d_in[7];
    const float* bo  = (const float*)d_in[8];
    float* out = (float*)d_out;

    char* p = (char*)d_ws;
    float* Wfold  = (float*)p; p += (size_t)F * HD * 4;
    float* bf0    = (float*)p; p += HD * 4;
    float* bf1    = (float*)p; p += HD * 4;
    short* WfoldT = (short*)p; p += (size_t)HD * F * 2;
    short* WhhT0  = (short*)p; p += (size_t)HD * HD * 2;
    short* WihT1  = (short*)p; p += (size_t)HD * HD * 2;
    short* WhhT1  = (short*)p; p += (size_t)HD * HD * 2;
    short* WoT    = (short*)p; p += (size_t)F * HD * 2;
    short* h0h    = (short*)p; p += (size_t)NSLOT * B * HD * 2;   // 24 MB
    short* h1h    = (short*)p; p += (size_t)NSLOT * B * HD * 2;   // 24 MB
    short* xbf    = (short*)p; p += (size_t)B * S * F * 2;
    u32*   sync   = (u32*)p;  p += 65536;

    hipMemsetAsync(sync, 0, 65536, stream);

    fold_kernel<<<256, 256, 0, stream>>>(Wh, Wih, Wfold);
    bias_kernel<<<64, 256, 0, stream>>>(bh, Wih, bih, bhh, bf0, bf1);
    transpose_cast<<<16, 256, 0, stream>>>(Wfold, WfoldT, F, HD);
    transpose_cast<<<256, 256, 0, stream>>>(Whh, WhhT0, HD, HD);
    transpose_cast<<<256, 256, 0, stream>>>(Wih + (size_t)HD * HD, WihT1, HD, HD);
    transpose_cast<<<256, 256, 0, stream>>>(Whh + (size_t)HD * HD, WhhT1, HD, HD);
    transpose_cast<<<16, 256, 0, stream>>>(Wo, WoT, HD, F);
    xcast<<<(B * S * F) / (256 * 4), 256, 0, stream>>>(x, xbf);

    u32* flags0 = sync;
    u32* flags1 = sync + 4096;
    void* args[] = {
        (void*)&xbf, (void*)&WfoldT, (void*)&bf0, (void*)&WhhT0,
        (void*)&WihT1, (void*)&WhhT1, (void*)&bf1,
        (void*)&h0h, (void*)&h1h, (void*)&flags0, (void*)&flags1
    };
    hipLaunchCooperativeKernel((void*)rnn_pers, dim3(256), dim3(512),
                               args, 131072, stream);

    outgemm<<<192, 256, 0, stream>>>(h1h, WoT, bo, out);
}

// Round 19
// 2171.221 us; speedup vs baseline: 2.1516x; 1.0016x over previous
//
#include <hip/hip_runtime.h>
#include <hip/hip_bf16.h>

#define B    256
#define S    192
#define F    64
#define HD   1024
#define PRED 48
#define TSTART (S - 1 - PRED)   // 143
#define NSLOT 48
#define BHD  ((size_t)B * HD)

typedef __attribute__((ext_vector_type(8))) short short8;
typedef __attribute__((ext_vector_type(4))) float f32x4;
typedef unsigned int u32;

static __device__ __forceinline__ short f2bf(float f) {
    __hip_bfloat16 h = __float2bfloat16(f);
    return *reinterpret_cast<short*>(&h);
}
static __device__ __forceinline__ f32x4 mfma16(short8 a, short8 b, f32x4 c) {
    return __builtin_amdgcn_mfma_f32_16x16x32_bf16(a, b, c, 0, 0, 0);
}
static __device__ __forceinline__ short8 ld8(const short* p) {
    return *reinterpret_cast<const short8*>(p);
}
// sc1 write-through store (MALL = device coherence point). R4-R18-proven.
// Readers: PLAIN cached loads on 48-slot-rotated fresh addresses.
static __device__ __forceinline__ void st_state(short* p, short v) {
    __hip_atomic_store(p, v, __ATOMIC_RELAXED, __HIP_MEMORY_SCOPE_AGENT);
}
static __device__ __forceinline__ u32 ld_flag(const u32* p) {
    return __hip_atomic_load(p, __ATOMIC_RELAXED, __HIP_MEMORY_SCOPE_AGENT);
}
static __device__ __forceinline__ void st_flag(u32* p, u32 v) {
    __hip_atomic_store(p, v, __ATOMIC_RELAXED, __HIP_MEMORY_SCOPE_AGENT);
}

// ---------------------------------------------------------------------------
// prep kernels (proven)
// ---------------------------------------------------------------------------
__global__ void fold_kernel(const float* __restrict__ Wh,
                            const float* __restrict__ Wih0,
                            float* __restrict__ Wfold) {
    const int n = (blockIdx.x & 3) * 256 + threadIdx.x;
    const int f = blockIdx.x >> 2;
    float a = 0.f;
#pragma unroll 16
    for (int k = 0; k < HD; ++k)
        a += Wh[f * HD + k] * Wih0[(size_t)k * HD + n];
    Wfold[f * HD + n] = a;
}

__global__ void bias_kernel(const float* __restrict__ bh,
                            const float* __restrict__ Wih0,
                            const float* __restrict__ bih,
                            const float* __restrict__ bhh,
                            float* __restrict__ bf0,
                            float* __restrict__ bf1) {
    __shared__ float red[256];
    const int nl = threadIdx.x & 15;
    const int kc = threadIdx.x >> 4;
    const int n  = blockIdx.x * 16 + nl;
    float a = 0.f;
#pragma unroll 8
    for (int k = kc * 64; k < kc * 64 + 64; ++k)
        a += bh[k] * Wih0[(size_t)k * HD + n];
    red[threadIdx.x] = a;
    __syncthreads();
    if (kc == 0) {
        float s = 0.f;
#pragma unroll
        for (int j = 0; j < 16; ++j) s += red[j * 16 + nl];
        bf0[n] = s + bih[n] + bhh[n];
        bf1[n] = bih[HD + n] + bhh[HD + n];
    }
}

__global__ void transpose_cast(const float* __restrict__ src,
                               short* __restrict__ dst, int K, int N) {
    __shared__ float tile[64][65];
    const int nk = K >> 6;
    const int bk = blockIdx.x % nk;
    const int bn = blockIdx.x / nk;
    const int i  = threadIdx.x;
    {
        const int c4 = (i & 15) * 4;
        for (int it = 0; it < 4; ++it) {
            const int k = (i >> 4) + it * 16;
            const float4 v = *reinterpret_cast<const float4*>(
                &src[(size_t)(bk * 64 + k) * N + bn * 64 + c4]);
            tile[k][c4 + 0] = v.x; tile[k][c4 + 1] = v.y;
            tile[k][c4 + 2] = v.z; tile[k][c4 + 3] = v.w;
        }
    }
    __syncthreads();
    {
        const int n  = i >> 2;
        const int kb = (i & 3) * 16;
        short* dp = &dst[(size_t)(bn * 64 + n) * K + bk * 64 + kb];
#pragma unroll
        for (int j = 0; j < 16; ++j) dp[j] = f2bf(tile[kb + j][n]);
    }
}

__global__ void xcast(const float* __restrict__ x, short* __restrict__ xb) {
    const size_t i = ((size_t)blockIdx.x * 256 + threadIdx.x) * 4;
    const float4 v = *reinterpret_cast<const float4*>(&x[i]);
    short4 o;
    o.x = f2bf(v.x); o.y = f2bf(v.y); o.z = f2bf(v.z); o.w = f2bf(v.w);
    *reinterpret_cast<short4*>(&xb[i]) = o;
}

// ---------------------------------------------------------------------------
// LDS layout (k-chunk-major, R11): addr = kc*2048 + r*64 + kg*16, 64KB/buffer.
// stage8: all 512 threads, 8 iters.  stage16: one 256-thread crew, 16 iters.
// ---------------------------------------------------------------------------
static __device__ __forceinline__ void stage8(char* lds, const short* __restrict__ src,
                                              int row0) {
    const int tid = threadIdx.x;
#pragma unroll
    for (int it = 0; it < 8; ++it) {
        const int idx = it * 512 + tid;
        const int r   = (idx >> 2) & 31;
        const int off = ((idx >> 7) << 6) + ((idx & 3) << 4);
        const f32x4 v = *reinterpret_cast<const f32x4*>(
            (const char*)src + (size_t)(row0 + r) * 2048 + off);
        *reinterpret_cast<f32x4*>(lds + (idx << 4)) = v;
    }
}
static __device__ __forceinline__ void stage16(char* lds, const short* __restrict__ src,
                                               int row0, int g) {
#pragma unroll
    for (int it = 0; it < 16; ++it) {
        const int idx = it * 256 + g;
        const int r   = (idx >> 2) & 31;
        const int off = ((idx >> 7) << 6) + ((idx & 3) << 4);
        const f32x4 v = *reinterpret_cast<const f32x4*>(
            (const char*)src + (size_t)(row0 + r) * 2048 + off);
        *reinterpret_cast<f32x4*>(lds + (idx << 4)) = v;
    }
}

// gemmLG: 16x16 frag, K=1024; A from LDS, B streamed 8-deep (R13-proven). L0.
static __device__ __forceinline__ f32x4 gemmLG(const char* ldsA,
                                               const short* __restrict__ bp,
                                               f32x4 acc_in) {
    f32x4 acc0 = acc_in, acc1 = {0.f,0.f,0.f,0.f};
    short8 b0[8], b1[8];
#pragma unroll
    for (int j = 0; j < 8; ++j) b0[j] = ld8(bp + j * 32);
#pragma unroll
    for (int c = 0; c < 4; ++c) {
        if (c < 3) {
            short8* nxt = (c & 1) ? b0 : b1;
#pragma unroll
            for (int j = 0; j < 8; ++j) nxt[j] = ld8(bp + (c + 1) * 256 + j * 32);
        }
        const short8* cur = (c & 1) ? b1 : b0;
#pragma unroll
        for (int j = 0; j < 8; ++j) {
            const short8 a = *reinterpret_cast<const short8*>(
                ldsA + (c * 8 + j) * 2048);
            if (j & 1) acc1 = mfma16(a, cur[j], acc1);
            else       acc0 = mfma16(a, cur[j], acc0);
        }
    }
    return acc0 + acc1;
}

// gemm2x: dual 16x16 frags (both row-halves) with SHARED B stream (one
// B-load feeds 2 MFMAs) — halves per-CU B-traffic, 2-chain ILP. L1.
static __device__ __forceinline__ void gemm2x(const char* lA0, const char* lA1,
                                              const short* __restrict__ bp,
                                              f32x4& accLo, f32x4& accHi) {
    short8 b0[8], b1[8];
#pragma unroll
    for (int j = 0; j < 8; ++j) b0[j] = ld8(bp + j * 32);
#pragma unroll
    for (int c = 0; c < 4; ++c) {
        if (c < 3) {
            short8* nxt = (c & 1) ? b0 : b1;
#pragma unroll
            for (int j = 0; j < 8; ++j) nxt[j] = ld8(bp + (c + 1) * 256 + j * 32);
        }
        const short8* cur = (c & 1) ? b1 : b0;
#pragma unroll
        for (int j = 0; j < 8; ++j) {
            const int ch = c * 8 + j;
            accLo = mfma16(*reinterpret_cast<const short8*>(lA0 + ch * 2048),
                           cur[j], accLo);
            accHi = mfma16(*reinterpret_cast<const short8*>(lA1 + ch * 2048),
                           cur[j], accHi);
        }
    }
}

// ---------------------------------------------------------------------------
// Persistent skewed recurrence. R19: L1 wave-split (waves 0-3: gemm1 ->
// f32 LDS partials; waves 4-7: gemm2 -> combine+tanh+store) + end-of-phase
// staging on BOTH layers (flags already set then -> polls cheap; waves 0-3
// stage next ldsA, waves 4-7 stage next ldsB concurrently). Second L1 flag
// (flagsG = stage-done) closes the L0 slot-overwrite WAR race.
// Dep order acyclic: L0(k)->flagsG(k-47); L1(k)->{flags0(k), flagsS(k)}.
// LDS: ldsA 64K | ldsB 64K | partial 8K = 136K.
// ---------------------------------------------------------------------------
__global__ __launch_bounds__(512, 1) void rnn_pers(
    const short* __restrict__ xbf,
    const short* __restrict__ WfoldT, const float* __restrict__ bf0,
    const short* __restrict__ WhhT0, const short* __restrict__ WihT1,
    const short* __restrict__ WhhT1, const float* __restrict__ bf1,
    short* h0h, short* h1h, u32* flags0, u32* flags1S, u32* flags1G) {

    extern __shared__ char lds[];                // 136 KB

    const int bid   = blockIdx.x;
    const int xcd   = bid & 7;
    const int u     = bid >> 3;
    const int layer = u & 1;
    const int rt    = ((xcd & 3) << 1) | ((u >> 1) & 1);   // 0..7
    const int ct    = ((xcd >> 2) << 3) | ((u >> 2) & 7);  // 0..15
    const int w     = threadIdx.x >> 6;
    const int l     = threadIdx.x & 63;
    const int lr    = l & 15, kg = l >> 4;
    const int row0  = rt * 32;
    const int tid   = threadIdx.x;

    if (layer == 0) {
        // ------- layer 0: 8 waves (mh,nq), R18 body + end-of-phase staging
        const int mh = w & 1, nq = w >> 1;
        const int m0 = row0 + mh * 16;
        const int col = ct * 64 + nq * 16 + lr;
        const int rb  = m0 + kg * 4;
        const char* ldsA = lds + mh * 1024 + lr * 64 + kg * 16;
        const float bb = bf0[col];
        u32* myflag = flags0 + (rt * 16 + ct) * 32;
        const short* wf = WfoldT + (size_t)col * F + kg * 8;
        const short8 wf0 = ld8(wf), wf1 = ld8(wf + 32);
        const short* whh0p = WhhT0 + (size_t)col * HD + kg * 8;

        for (int k = 0; k < S - 1; ++k) {
            const short* xp = xbf + ((size_t)(m0 + lr) * S + k) * F + kg * 8;
            f32x4 acc = {0.f, 0.f, 0.f, 0.f};
            acc = mfma16(ld8(xp),      wf0, acc);
            acc = mfma16(ld8(xp + 32), wf1, acc);
            if (k > 0) acc = gemmLG(ldsA, whh0p, acc);   // ldsA = h0(k-1)
            short* hd = h0h + (size_t)(k % NSLOT) * BHD;
#pragma unroll
            for (int r = 0; r < 4; ++r)
                st_state(&hd[(size_t)(rb + r) * HD + col],
                         f2bf(tanhf(acc[r] + bb)));
            __syncthreads();                      // drain sc1 stores (vmcnt 0)
            if (tid == 0) st_flag(myflag, (u32)(k + 1));
            if (k + 1 < S - 1) {
                // polls for next phase: peers' h0(k) stores; WAR vs L1 staging
                if (tid < 16) {
                    const u32* f = flags0 + (rt * 16 + tid) * 32;
                    while (ld_flag(f) < (u32)(k + 1)) __builtin_amdgcn_s_sleep(1);
                } else if (tid >= 64 && tid < 80 && (k + 1) >= 48) {
                    const u32* f = flags1G + (rt * 16 + (tid - 64)) * 32;
                    while (ld_flag(f) < (u32)(k + 1 - 47)) __builtin_amdgcn_s_sleep(1);
                }
                __syncthreads();
                stage8(lds, h0h + (size_t)(k % NSLOT) * BHD, row0);  // ldsA=h0(k)
                __syncthreads();
            }
        }
    } else {
        // ------- layer 1: wave-split. half 0 (w<4): gemm1 -> partials +
        // stage next ldsA. half 1 (w>=4): gemm2 -> combine -> store + stage ldsB.
        char*  ldsB = lds + 65536;
        float* ldsP = reinterpret_cast<float*>(lds + 131072);
        const int half = w >> 2;
        const int wq   = w & 3;
        const int g256 = tid & 255;
        const int col  = ct * 64 + wq * 16 + lr;
        const char* lA0 = lds  + lr * 64 + kg * 16;          // mh=0
        const char* lA1 = lds  + 1024 + lr * 64 + kg * 16;   // mh=1
        const char* lB0 = ldsB + lr * 64 + kg * 16;
        const char* lB1 = ldsB + 1024 + lr * 64 + kg * 16;
        const short* wih1p = WihT1 + (size_t)col * HD + kg * 8;
        const short* whh1p = WhhT1 + (size_t)col * HD + kg * 8;
        const float bb = bf1[col];
        u32* myflagS = flags1S + (rt * 16 + ct) * 32;
        u32* myflagG = flags1G + (rt * 16 + ct) * 32;

        // prologue: phase-0 no-op flag; stage ldsA = h0(0)
        if (tid == 0) st_flag(myflagS, 1u);
        if (tid < 16) {
            const u32* f = flags0 + (rt * 16 + tid) * 32;
            while (ld_flag(f) < 1u) __builtin_amdgcn_s_sleep(1);
        }
        __syncthreads();
        stage8(lds, h0h, row0);                   // slot 0 = h0(0)
        __syncthreads();
        if (tid == 0) st_flag(myflagG, 1u);

        for (int k = 1; k < S; ++k) {
            const int t = k - 1;
            f32x4 aLo = {0.f,0.f,0.f,0.f}, aHi = {0.f,0.f,0.f,0.f};
            if (half == 0) {
                gemm2x(lA0, lA1, wih1p, aLo, aHi);   // gemm1: h0(k-1)@Wih1
#pragma unroll
                for (int r = 0; r < 4; ++r) {
                    ldsP[(kg * 4 + r) * 64 + wq * 16 + lr]        = aLo[r];
                    ldsP[(16 + kg * 4 + r) * 64 + wq * 16 + lr]   = aHi[r];
                }
            } else if (t > 0) {
                gemm2x(lB0, lB1, whh1p, aLo, aHi);   // gemm2: h1(t-1)@Whh1
            }
            __syncthreads();                       // partials visible
            if (half == 1) {
                short* hd = h1h + (size_t)(t % NSLOT) * BHD;
#pragma unroll
                for (int r = 0; r < 4; ++r) {
                    const float vLo = tanhf(aLo[r] + bb
                        + ldsP[(kg * 4 + r) * 64 + wq * 16 + lr]);
                    const float vHi = tanhf(aHi[r] + bb
                        + ldsP[(16 + kg * 4 + r) * 64 + wq * 16 + lr]);
                    st_state(&hd[(size_t)(row0 + kg * 4 + r) * HD + col], f2bf(vLo));
                    st_state(&hd[(size_t)(row0 + 16 + kg * 4 + r) * HD + col], f2bf(vHi));
                }
            }
            __syncthreads();                       // drain stores; P reads done
            if (tid == 0) st_flag(myflagS, (u32)(k + 1));
            if (k + 1 < S) {
                if (tid < 16) {
                    const u32* f = flags0 + (rt * 16 + tid) * 32;
                    while (ld_flag(f) < (u32)(k + 1)) __builtin_amdgcn_s_sleep(1);
                } else if (tid >= 64 && tid < 80) {
                    const u32* f = flags1S + (rt * 16 + (tid - 64)) * 32;
                    while (ld_flag(f) < (u32)(k + 1)) __builtin_amdgcn_s_sleep(1);
                }
                __syncthreads();
                if (half == 0)
                    stage16(lds,  h0h + (size_t)(k % NSLOT) * BHD, row0, g256);
                else
                    stage16(ldsB, h1h + (size_t)((k - 1) % NSLOT) * BHD, row0, g256);
                __syncthreads();
                if (tid == 0) st_flag(myflagG, (u32)(k + 1));
            }
        }
    }
}

// ---------------------------------------------------------------------------
// outgemm: out[b][p][f] = relu(h1(143+p)[b]) @ WoT + bo (history slots,
// bijective (143+p)%48; slots t>=143 never overwritten). Kernel boundary
// gives coherence.
// ---------------------------------------------------------------------------
__global__ __launch_bounds__(256) void outgemm(
    const short* __restrict__ h1h, const short* __restrict__ WoT,
    const float* __restrict__ bo, float* __restrict__ out) {
    const int w = threadIdx.x >> 6, l = threadIdx.x & 63;
    const int lr = l & 15, kg = l >> 4;
    const int m0 = blockIdx.x * 64 + w * 16;
    const int arow = m0 + lr;                 // b*48+p
    const u32 bidx = (u32)arow / 48u;
    const u32 p    = (u32)arow % 48u;
    const u32 slot = (143u + p) % 48u;

    f32x4 acc[4] = {{0.f,0.f,0.f,0.f},{0.f,0.f,0.f,0.f},
                    {0.f,0.f,0.f,0.f},{0.f,0.f,0.f,0.f}};
    const short* ap = h1h + ((size_t)slot * B + bidx) * HD + kg * 8;
    const short* bp = WoT + (size_t)lr * HD + kg * 8;
#pragma unroll 4
    for (int k0 = 0; k0 < HD; k0 += 32) {
        short8 a = ld8(ap + k0);
#pragma unroll
        for (int j = 0; j < 8; ++j) a[j] = (a[j] < 0) ? (short)0 : a[j];  // relu
#pragma unroll
        for (int c = 0; c < 4; ++c)
            acc[c] = mfma16(a, ld8(bp + (size_t)c * 16 * HD + k0), acc[c]);
    }
    const int rb = m0 + kg * 4;
#pragma unroll
    for (int c = 0; c < 4; ++c) {
        const float bbv = bo[c * 16 + lr];
#pragma unroll
        for (int r = 0; r < 4; ++r)
            out[(size_t)(rb + r) * F + c * 16 + lr] = acc[c][r] + bbv;
    }
}

// ---------------------------------------------------------------------------
extern "C" void kernel_launch(void* const* d_in, const int* in_sizes, int n_in,
                              void* d_out, int out_size, void* d_ws, size_t ws_size,
                              hipStream_t stream) {
    const float* x   = (const float*)d_in[0];
    const float* Wh  = (const float*)d_in[1];
    const float* bh  = (const float*)d_in[2];
    const float* Wih = (const float*)d_in[3];
    const float* Whh = (const float*)d_in[4];
    const float* bih = (const float*)d_in[5];
    const float* bhh = (const float*)d_in[6];
    const float* Wo  = (const float*)d_in[7];
    const float* bo  = (const float*)d_in[8];
    float* out = (float*)d_out;

    char* p = (char*)d_ws;
    float* Wfold  = (float*)p; p += (size_t)F * HD * 4;
    float* bf0    = (float*)p; p += HD * 4;
    float* bf1    = (float*)p; p += HD * 4;
    short* WfoldT = (short*)p; p += (size_t)HD * F * 2;
    short* WhhT0  = (short*)p; p += (size_t)HD * HD * 2;
    short* WihT1  = (short*)p; p += (size_t)HD * HD * 2;
    short* WhhT1  = (short*)p; p += (size_t)HD * HD * 2;
    short* WoT    = (short*)p; p += (size_t)F * HD * 2;
    short* h0h    = (short*)p; p += (size_t)NSLOT * B * HD * 2;   // 24 MB
    short* h1h    = (short*)p; p += (size_t)NSLOT * B * HD * 2;   // 24 MB
    short* xbf    = (short*)p; p += (size_t)B * S * F * 2;
    u32*   sync   = (u32*)p;  p += 65536;
    // sync: flags0 @0 | flags1S @+16KB | flags1G @+32KB (128 flags x 128B each)

    hipMemsetAsync(sync, 0, 65536, stream);

    fold_kernel<<<256, 256, 0, stream>>>(Wh, Wih, Wfold);
    bias_kernel<<<64, 256, 0, stream>>>(bh, Wih, bih, bhh, bf0, bf1);
    transpose_cast<<<16, 256, 0, stream>>>(Wfold, WfoldT, F, HD);
    transpose_cast<<<256, 256, 0, stream>>>(Whh, WhhT0, HD, HD);
    transpose_cast<<<256, 256, 0, stream>>>(Wih + (size_t)HD * HD, WihT1, HD, HD);
    transpose_cast<<<256, 256, 0, stream>>>(Whh + (size_t)HD * HD, WhhT1, HD, HD);
    transpose_cast<<<16, 256, 0, stream>>>(Wo, WoT, HD, F);
    xcast<<<(B * S * F) / (256 * 4), 256, 0, stream>>>(x, xbf);

    u32* flags0  = sync;
    u32* flags1S = sync + 4096;
    u32* flags1G = sync + 8192;
    void* args[] = {
        (void*)&xbf, (void*)&WfoldT, (void*)&bf0, (void*)&WhhT0,
        (void*)&WihT1, (void*)&WhhT1, (void*)&bf1,
        (void*)&h0h, (void*)&h1h,
        (void*)&flags0, (void*)&flags1S, (void*)&flags1G
    };
    hipLaunchCooperativeKernel((void*)rnn_pers, dim3(256), dim3(512),
                               args, 139264, stream);

    outgemm<<<192, 256, 0, stream>>>(h1h, WoT, bo, out);
}

// Round 20
// 2134.611 us; speedup vs baseline: 2.1885x; 1.0172x over previous
//
#include <hip/hip_runtime.h>
#include <hip/hip_bf16.h>

#define B    256
#define S    192
#define F    64
#define HD   1024
#define PRED 48
#define TSTART (S - 1 - PRED)   // 143
#define NSLOT 48
#define BHD  ((size_t)B * HD)

typedef __attribute__((ext_vector_type(8))) short short8;
typedef __attribute__((ext_vector_type(4))) float f32x4;
typedef unsigned int u32;

static __device__ __forceinline__ short f2bf(float f) {
    __hip_bfloat16 h = __float2bfloat16(f);
    return *reinterpret_cast<short*>(&h);
}
static __device__ __forceinline__ f32x4 mfma16(short8 a, short8 b, f32x4 c) {
    return __builtin_amdgcn_mfma_f32_16x16x32_bf16(a, b, c, 0, 0, 0);
}
static __device__ __forceinline__ short8 ld8(const short* p) {
    return *reinterpret_cast<const short8*>(p);
}
// sc1 write-through store (MALL = device coherence point). R4-R19-proven.
// Readers: PLAIN cached loads on 48-slot-rotated fresh addresses.
static __device__ __forceinline__ void st_state(short* p, short v) {
    __hip_atomic_store(p, v, __ATOMIC_RELAXED, __HIP_MEMORY_SCOPE_AGENT);
}
static __device__ __forceinline__ u32 ld_flag(const u32* p) {
    return __hip_atomic_load(p, __ATOMIC_RELAXED, __HIP_MEMORY_SCOPE_AGENT);
}
static __device__ __forceinline__ void st_flag(u32* p, u32 v) {
    __hip_atomic_store(p, v, __ATOMIC_RELAXED, __HIP_MEMORY_SCOPE_AGENT);
}

// ---------------------------------------------------------------------------
// prep kernels (proven)
// ---------------------------------------------------------------------------
__global__ void fold_kernel(const float* __restrict__ Wh,
                            const float* __restrict__ Wih0,
                            float* __restrict__ Wfold) {
    const int n = (blockIdx.x & 3) * 256 + threadIdx.x;
    const int f = blockIdx.x >> 2;
    float a = 0.f;
#pragma unroll 16
    for (int k = 0; k < HD; ++k)
        a += Wh[f * HD + k] * Wih0[(size_t)k * HD + n];
    Wfold[f * HD + n] = a;
}

__global__ void bias_kernel(const float* __restrict__ bh,
                            const float* __restrict__ Wih0,
                            const float* __restrict__ bih,
                            const float* __restrict__ bhh,
                            float* __restrict__ bf0,
                            float* __restrict__ bf1) {
    __shared__ float red[256];
    const int nl = threadIdx.x & 15;
    const int kc = threadIdx.x >> 4;
    const int n  = blockIdx.x * 16 + nl;
    float a = 0.f;
#pragma unroll 8
    for (int k = kc * 64; k < kc * 64 + 64; ++k)
        a += bh[k] * Wih0[(size_t)k * HD + n];
    red[threadIdx.x] = a;
    __syncthreads();
    if (kc == 0) {
        float s = 0.f;
#pragma unroll
        for (int j = 0; j < 16; ++j) s += red[j * 16 + nl];
        bf0[n] = s + bih[n] + bhh[n];
        bf1[n] = bih[HD + n] + bhh[HD + n];
    }
}

__global__ void transpose_cast(const float* __restrict__ src,
                               short* __restrict__ dst, int K, int N) {
    __shared__ float tile[64][65];
    const int nk = K >> 6;
    const int bk = blockIdx.x % nk;
    const int bn = blockIdx.x / nk;
    const int i  = threadIdx.x;
    {
        const int c4 = (i & 15) * 4;
        for (int it = 0; it < 4; ++it) {
            const int k = (i >> 4) + it * 16;
            const float4 v = *reinterpret_cast<const float4*>(
                &src[(size_t)(bk * 64 + k) * N + bn * 64 + c4]);
            tile[k][c4 + 0] = v.x; tile[k][c4 + 1] = v.y;
            tile[k][c4 + 2] = v.z; tile[k][c4 + 3] = v.w;
        }
    }
    __syncthreads();
    {
        const int n  = i >> 2;
        const int kb = (i & 3) * 16;
        short* dp = &dst[(size_t)(bn * 64 + n) * K + bk * 64 + kb];
#pragma unroll
        for (int j = 0; j < 16; ++j) dp[j] = f2bf(tile[kb + j][n]);
    }
}

__global__ void xcast(const float* __restrict__ x, short* __restrict__ xb) {
    const size_t i = ((size_t)blockIdx.x * 256 + threadIdx.x) * 4;
    const float4 v = *reinterpret_cast<const float4*>(&x[i]);
    short4 o;
    o.x = f2bf(v.x); o.y = f2bf(v.y); o.z = f2bf(v.z); o.w = f2bf(v.w);
    *reinterpret_cast<short4*>(&xb[i]) = o;
}

// ---------------------------------------------------------------------------
// LDS layout (k-chunk-major, R11): addr = kc*2048 + r*64 + kg*16, 64KB/buffer.
// stage8: all 512 threads, 8 iters.  stage16: one 256-thread crew, 16 iters.
// ---------------------------------------------------------------------------
static __device__ __forceinline__ void stage8(char* lds, const short* __restrict__ src,
                                              int row0) {
    const int tid = threadIdx.x;
#pragma unroll
    for (int it = 0; it < 8; ++it) {
        const int idx = it * 512 + tid;
        const int r   = (idx >> 2) & 31;
        const int off = ((idx >> 7) << 6) + ((idx & 3) << 4);
        const f32x4 v = *reinterpret_cast<const f32x4*>(
            (const char*)src + (size_t)(row0 + r) * 2048 + off);
        *reinterpret_cast<f32x4*>(lds + (idx << 4)) = v;
    }
}
static __device__ __forceinline__ void stage16(char* lds, const short* __restrict__ src,
                                               int row0, int g) {
#pragma unroll
    for (int it = 0; it < 16; ++it) {
        const int idx = it * 256 + g;
        const int r   = (idx >> 2) & 31;
        const int off = ((idx >> 7) << 6) + ((idx & 3) << 4);
        const f32x4 v = *reinterpret_cast<const f32x4*>(
            (const char*)src + (size_t)(row0 + r) * 2048 + off);
        *reinterpret_cast<f32x4*>(lds + (idx << 4)) = v;
    }
}

// gemmLG: 16x16 frag, K=1024; A from LDS, B streamed 8-deep (R13-proven). L0.
static __device__ __forceinline__ f32x4 gemmLG(const char* ldsA,
                                               const short* __restrict__ bp,
                                               f32x4 acc_in) {
    f32x4 acc0 = acc_in, acc1 = {0.f,0.f,0.f,0.f};
    short8 b0[8], b1[8];
#pragma unroll
    for (int j = 0; j < 8; ++j) b0[j] = ld8(bp + j * 32);
#pragma unroll
    for (int c = 0; c < 4; ++c) {
        if (c < 3) {
            short8* nxt = (c & 1) ? b0 : b1;
#pragma unroll
            for (int j = 0; j < 8; ++j) nxt[j] = ld8(bp + (c + 1) * 256 + j * 32);
        }
        const short8* cur = (c & 1) ? b1 : b0;
#pragma unroll
        for (int j = 0; j < 8; ++j) {
            const short8 a = *reinterpret_cast<const short8*>(
                ldsA + (c * 8 + j) * 2048);
            if (j & 1) acc1 = mfma16(a, cur[j], acc1);
            else       acc0 = mfma16(a, cur[j], acc0);
        }
    }
    return acc0 + acc1;
}

// gemm2x: dual 16x16 frags (both row-halves) with SHARED B stream (one
// B-load feeds 2 MFMAs) — halves per-CU B-traffic, 2-chain ILP. L1.
static __device__ __forceinline__ void gemm2x(const char* lA0, const char* lA1,
                                              const short* __restrict__ bp,
                                              f32x4& accLo, f32x4& accHi) {
    short8 b0[8], b1[8];
#pragma unroll
    for (int j = 0; j < 8; ++j) b0[j] = ld8(bp + j * 32);
#pragma unroll
    for (int c = 0; c < 4; ++c) {
        if (c < 3) {
            short8* nxt = (c & 1) ? b0 : b1;
#pragma unroll
            for (int j = 0; j < 8; ++j) nxt[j] = ld8(bp + (c + 1) * 256 + j * 32);
        }
        const short8* cur = (c & 1) ? b1 : b0;
#pragma unroll
        for (int j = 0; j < 8; ++j) {
            const int ch = c * 8 + j;
            accLo = mfma16(*reinterpret_cast<const short8*>(lA0 + ch * 2048),
                           cur[j], accLo);
            accHi = mfma16(*reinterpret_cast<const short8*>(lA1 + ch * 2048),
                           cur[j], accHi);
        }
    }
}

// ---------------------------------------------------------------------------
// Persistent skewed recurrence — R20 consolidation of the measured best:
// R15 rt-locality bid map (FETCH 4x), R11 flag protocol, R19 L1 wave-split
// (gemm1 || gemm2) + end-of-phase staging. Delta vs R19: flagsG REMOVED —
// L0's slot-overwrite WAR uses R18's proven flags1S(k-45) bound instead
// (L1 completing phase k-45 implies its staging of h0(k-46..) is done,
// since R19/R18 staging for phase p happens at/before start of phase p).
// Dep graph acyclic: L0(k) -> flags1S(k-45); L1(k) -> flags0(k), flags1S(k).
// LDS: ldsA 64K | ldsB 64K | partial 8K = 136K.
// ---------------------------------------------------------------------------
__global__ __launch_bounds__(512, 1) void rnn_pers(
    const short* __restrict__ xbf,
    const short* __restrict__ WfoldT, const float* __restrict__ bf0,
    const short* __restrict__ WhhT0, const short* __restrict__ WihT1,
    const short* __restrict__ WhhT1, const float* __restrict__ bf1,
    short* h0h, short* h1h, u32* flags0, u32* flags1S) {

    extern __shared__ char lds[];                // 136 KB

    const int bid   = blockIdx.x;
    const int xcd   = bid & 7;
    const int u     = bid >> 3;
    const int layer = u & 1;
    const int rt    = ((xcd & 3) << 1) | ((u >> 1) & 1);   // 0..7
    const int ct    = ((xcd >> 2) << 3) | ((u >> 2) & 7);  // 0..15
    const int w     = threadIdx.x >> 6;
    const int l     = threadIdx.x & 63;
    const int lr    = l & 15, kg = l >> 4;
    const int row0  = rt * 32;
    const int tid   = threadIdx.x;

    if (layer == 0) {
        // ------- layer 0: 8 waves (mh,nq); end-of-phase staging
        const int mh = w & 1, nq = w >> 1;
        const int m0 = row0 + mh * 16;
        const int col = ct * 64 + nq * 16 + lr;
        const int rb  = m0 + kg * 4;
        const char* ldsA = lds + mh * 1024 + lr * 64 + kg * 16;
        const float bb = bf0[col];
        u32* myflag = flags0 + (rt * 16 + ct) * 32;
        const short* wf = WfoldT + (size_t)col * F + kg * 8;
        const short8 wf0 = ld8(wf), wf1 = ld8(wf + 32);
        const short* whh0p = WhhT0 + (size_t)col * HD + kg * 8;

        for (int k = 0; k < S - 1; ++k) {
            const short* xp = xbf + ((size_t)(m0 + lr) * S + k) * F + kg * 8;
            f32x4 acc = {0.f, 0.f, 0.f, 0.f};
            acc = mfma16(ld8(xp),      wf0, acc);
            acc = mfma16(ld8(xp + 32), wf1, acc);
            if (k > 0) acc = gemmLG(ldsA, whh0p, acc);   // ldsA = h0(k-1)
            short* hd = h0h + (size_t)(k % NSLOT) * BHD;
#pragma unroll
            for (int r = 0; r < 4; ++r)
                st_state(&hd[(size_t)(rb + r) * HD + col],
                         f2bf(tanhf(acc[r] + bb)));
            __syncthreads();                      // drain sc1 stores (vmcnt 0)
            if (tid == 0) st_flag(myflag, (u32)(k + 1));
            if (k + 1 < S - 1) {
                // polls for next phase: peers' h0(k) stores; WAR vs L1 progress
                if (tid < 16) {
                    const u32* f = flags0 + (rt * 16 + tid) * 32;
                    while (ld_flag(f) < (u32)(k + 1)) __builtin_amdgcn_s_sleep(1);
                } else if (tid >= 64 && tid < 80 && (k + 1) >= 46) {
                    const u32* f = flags1S + (rt * 16 + (tid - 64)) * 32;
                    while (ld_flag(f) < (u32)(k + 1 - 45)) __builtin_amdgcn_s_sleep(1);
                }
                __syncthreads();
                stage8(lds, h0h + (size_t)(k % NSLOT) * BHD, row0);  // ldsA=h0(k)
                __syncthreads();
            }
        }
    } else {
        // ------- layer 1: wave-split. half 0 (w<4): gemm1 -> partials +
        // stage next ldsA. half 1 (w>=4): gemm2 -> combine -> store + stage ldsB.
        char*  ldsB = lds + 65536;
        float* ldsP = reinterpret_cast<float*>(lds + 131072);
        const int half = w >> 2;
        const int wq   = w & 3;
        const int g256 = tid & 255;
        const int col  = ct * 64 + wq * 16 + lr;
        const char* lA0 = lds  + lr * 64 + kg * 16;          // mh=0
        const char* lA1 = lds  + 1024 + lr * 64 + kg * 16;   // mh=1
        const char* lB0 = ldsB + lr * 64 + kg * 16;
        const char* lB1 = ldsB + 1024 + lr * 64 + kg * 16;
        const short* wih1p = WihT1 + (size_t)col * HD + kg * 8;
        const short* whh1p = WhhT1 + (size_t)col * HD + kg * 8;
        const float bb = bf1[col];
        u32* myflagS = flags1S + (rt * 16 + ct) * 32;

        // prologue: stage ldsA = h0(0); then announce phase-"1" readiness
        if (tid < 16) {
            const u32* f = flags0 + (rt * 16 + tid) * 32;
            while (ld_flag(f) < 1u) __builtin_amdgcn_s_sleep(1);
        }
        __syncthreads();
        stage8(lds, h0h, row0);                   // slot 0 = h0(0)
        __syncthreads();
        if (tid == 0) st_flag(myflagS, 1u);

        for (int k = 1; k < S; ++k) {
            const int t = k - 1;
            f32x4 aLo = {0.f,0.f,0.f,0.f}, aHi = {0.f,0.f,0.f,0.f};
            if (half == 0) {
                gemm2x(lA0, lA1, wih1p, aLo, aHi);   // gemm1: h0(k-1)@Wih1
#pragma unroll
                for (int r = 0; r < 4; ++r) {
                    ldsP[(kg * 4 + r) * 64 + wq * 16 + lr]        = aLo[r];
                    ldsP[(16 + kg * 4 + r) * 64 + wq * 16 + lr]   = aHi[r];
                }
            } else if (t > 0) {
                gemm2x(lB0, lB1, whh1p, aLo, aHi);   // gemm2: h1(t-1)@Whh1
            }
            __syncthreads();                       // partials visible
            if (half == 1) {
                short* hd = h1h + (size_t)(t % NSLOT) * BHD;
#pragma unroll
                for (int r = 0; r < 4; ++r) {
                    const float vLo = tanhf(aLo[r] + bb
                        + ldsP[(kg * 4 + r) * 64 + wq * 16 + lr]);
                    const float vHi = tanhf(aHi[r] + bb
                        + ldsP[(16 + kg * 4 + r) * 64 + wq * 16 + lr]);
                    st_state(&hd[(size_t)(row0 + kg * 4 + r) * HD + col], f2bf(vLo));
                    st_state(&hd[(size_t)(row0 + 16 + kg * 4 + r) * HD + col], f2bf(vHi));
                }
            }
            __syncthreads();                       // drain stores; P reads done
            if (tid == 0) st_flag(myflagS, (u32)(k + 1));
            if (k + 1 < S) {
                if (tid < 16) {
                    const u32* f = flags0 + (rt * 16 + tid) * 32;
                    while (ld_flag(f) < (u32)(k + 1)) __builtin_amdgcn_s_sleep(1);
                } else if (tid >= 64 && tid < 80) {
                    const u32* f = flags1S + (rt * 16 + (tid - 64)) * 32;
                    while (ld_flag(f) < (u32)(k + 1)) __builtin_amdgcn_s_sleep(1);
                }
                __syncthreads();
                if (half == 0)
                    stage16(lds,  h0h + (size_t)(k % NSLOT) * BHD, row0, g256);
                else
                    stage16(ldsB, h1h + (size_t)((k - 1) % NSLOT) * BHD, row0, g256);
                __syncthreads();
            }
        }
    }
}

// ---------------------------------------------------------------------------
// outgemm: out[b][p][f] = relu(h1(143+p)[b]) @ WoT + bo (history slots,
// bijective (143+p)%48; slots t>=143 never overwritten). Kernel boundary
// gives coherence.
// ---------------------------------------------------------------------------
__global__ __launch_bounds__(256) void outgemm(
    const short* __restrict__ h1h, const short* __restrict__ WoT,
    const float* __restrict__ bo, float* __restrict__ out) {
    const int w = threadIdx.x >> 6, l = threadIdx.x & 63;
    const int lr = l & 15, kg = l >> 4;
    const int m0 = blockIdx.x * 64 + w * 16;
    const int arow = m0 + lr;                 // b*48+p
    const u32 bidx = (u32)arow / 48u;
    const u32 p    = (u32)arow % 48u;
    const u32 slot = (143u + p) % 48u;

    f32x4 acc[4] = {{0.f,0.f,0.f,0.f},{0.f,0.f,0.f,0.f},
                    {0.f,0.f,0.f,0.f},{0.f,0.f,0.f,0.f}};
    const short* ap = h1h + ((size_t)slot * B + bidx) * HD + kg * 8;
    const short* bp = WoT + (size_t)lr * HD + kg * 8;
#pragma unroll 4
    for (int k0 = 0; k0 < HD; k0 += 32) {
        short8 a = ld8(ap + k0);
#pragma unroll
        for (int j = 0; j < 8; ++j) a[j] = (a[j] < 0) ? (short)0 : a[j];  // relu
#pragma unroll
        for (int c = 0; c < 4; ++c)
            acc[c] = mfma16(a, ld8(bp + (size_t)c * 16 * HD + k0), acc[c]);
    }
    const int rb = m0 + kg * 4;
#pragma unroll
    for (int c = 0; c < 4; ++c) {
        const float bbv = bo[c * 16 + lr];
#pragma unroll
        for (int r = 0; r < 4; ++r)
            out[(size_t)(rb + r) * F + c * 16 + lr] = acc[c][r] + bbv;
    }
}

// ---------------------------------------------------------------------------
extern "C" void kernel_launch(void* const* d_in, const int* in_sizes, int n_in,
                              void* d_out, int out_size, void* d_ws, size_t ws_size,
                              hipStream_t stream) {
    const float* x   = (const float*)d_in[0];
    const float* Wh  = (const float*)d_in[1];
    const float* bh  = (const float*)d_in[2];
    const float* Wih = (const float*)d_in[3];
    const float* Whh = (const float*)d_in[4];
    const float* bih = (const float*)d_in[5];
    const float* bhh = (const float*)d_in[6];
    const float* Wo  = (const float*)d_in[7];
    const float* bo  = (const float*)d_in[8];
    float* out = (float*)d_out;

    char* p = (char*)d_ws;
    float* Wfold  = (float*)p; p += (size_t)F * HD * 4;
    float* bf0    = (float*)p; p += HD * 4;
    float* bf1    = (float*)p; p += HD * 4;
    short* WfoldT = (short*)p; p += (size_t)HD * F * 2;
    short* WhhT0  = (short*)p; p += (size_t)HD * HD * 2;
    short* WihT1  = (short*)p; p += (size_t)HD * HD * 2;
    short* WhhT1  = (short*)p; p += (size_t)HD * HD * 2;
    short* WoT    = (short*)p; p += (size_t)F * HD * 2;
    short* h0h    = (short*)p; p += (size_t)NSLOT * B * HD * 2;   // 24 MB
    short* h1h    = (short*)p; p += (size_t)NSLOT * B * HD * 2;   // 24 MB
    short* xbf    = (short*)p; p += (size_t)B * S * F * 2;
    u32*   sync   = (u32*)p;  p += 65536;
    // sync: flags0 @0 | flags1S @+16KB (128 flags x 128B each)

    hipMemsetAsync(sync, 0, 65536, stream);

    fold_kernel<<<256, 256, 0, stream>>>(Wh, Wih, Wfold);
    bias_kernel<<<64, 256, 0, stream>>>(bh, Wih, bih, bhh, bf0, bf1);
    transpose_cast<<<16, 256, 0, stream>>>(Wfold, WfoldT, F, HD);
    transpose_cast<<<256, 256, 0, stream>>>(Whh, WhhT0, HD, HD);
    transpose_cast<<<256, 256, 0, stream>>>(Wih + (size_t)HD * HD, WihT1, HD, HD);
    transpose_cast<<<256, 256, 0, stream>>>(Whh + (size_t)HD * HD, WhhT1, HD, HD);
    transpose_cast<<<16, 256, 0, stream>>>(Wo, WoT, HD, F);
    xcast<<<(B * S * F) / (256 * 4), 256, 0, stream>>>(x, xbf);

    u32* flags0  = sync;
    u32* flags1S = sync + 4096;
    void* args[] = {
        (void*)&xbf, (void*)&WfoldT, (void*)&bf0, (void*)&WhhT0,
        (void*)&WihT1, (void*)&WhhT1, (void*)&bf1,
        (void*)&h0h, (void*)&h1h,
        (void*)&flags0, (void*)&flags1S
    };
    hipLaunchCooperativeKernel((void*)rnn_pers, dim3(256), dim3(512),
                               args, 139264, stream);

    outgemm<<<192, 256, 0, stream>>>(h1h, WoT, bo, out);
}